// Round 3
// baseline (435.757 us; speedup 1.0000x reference)
//
#include <hip/hip_runtime.h>
#include <hip/hip_bf16.h>

typedef __hip_bfloat16 bf16;
typedef __attribute__((ext_vector_type(8))) short short8;
typedef __attribute__((ext_vector_type(4))) short s4v;
typedef __attribute__((ext_vector_type(4))) float float4v;

#define NN 512      // image N
#define NA 30       // angles
#define ND 729      // detectors
#define NB 2        // batch
#define NL 3        // iterations
#define BNN (NB*NN*NN)     // 524288
#define BAD (NB*NA*ND)     // 43740

// padded image layout: PH x PW, logical (0,0) at physical (2,2)
#define PW 520
#define PH 516
#define PIMG (PH*PW)       // 268320
#define POFF (2*PW + 2)    // 1042

// ---- workspace float offsets ----
#define O_CS  0
#define O_SN  32
#define O_ICS 64                      // 1/cs per angle
#define O_ISN 96                      // -1/sn per angle
#define O_XP  128                     // 2*PIMG  (current X, padded)
#define O_YP  (O_XP + 2*PIMG)         // 2*PIMG  (Y = X + noise, padded)
#define O_YPT (O_YP + 2*PIMG)         // 2*PIMG  (transposed Y, padded)
#define O_SP  (O_YPT + 2*PIMG)        // BAD
#define O_Q   (O_SP + BAD)            // BAD
#define O_WR  (O_Q + BAD)             // bf16 region: 69120 bf16 = 34560 floats
#define O_H   (((O_WR + 34560) + 15) & ~15)
#define H_FLOATS (NB * 32 * NN * NN / 2)

// repacked weight bf16 offsets within WR region
#define WR2_OFF 0                   // [n][tap][co32][ci32] : 3*9216
#define WR3_OFF 27648               // 3*9216
#define WR4_OFF 55296               // [n][tap][co16][ci32] : 3*4608 (co>0 zero)

// unaligned 8B load (pair of adjacent floats) -> global_load_dwordx2
__device__ __forceinline__ float2 ld2u(const float* p)
{
    float2 r;
    __builtin_memcpy(&r, p, 8);
    return r;
}

// ---- setup: angles + reciprocals + weight repack + image padding, one kernel ----
__global__ void k_prep(const float* __restrict__ theta,
                       const float* __restrict__ w2, const float* __restrict__ w3,
                       const float* __restrict__ w4, const float* __restrict__ x0,
                       float* __restrict__ ws, bf16* __restrict__ wr)
{
    int idx = blockIdx.x * 256 + threadIdx.x;
    if (idx < NA) {
        float t = theta[idx];
        float cs = cosf(t), sn = sinf(t);
        ws[O_CS + idx] = cs;
        ws[O_SN + idx] = sn;
        ws[O_ICS + idx] = 1.0f / cs;      // +-inf ok
        ws[O_ISN + idx] = -1.0f / sn;     // +-inf ok
    }
    if (idx < 2 * 27648) {
        const float* w = (idx < 27648) ? w2 : w3;
        int base = (idx < 27648) ? WR2_OFF : WR3_OFF;
        int r = idx % 27648;
        int n = r / 9216; int r2 = r % 9216;
        int tap = r2 / 1024; int r3 = r2 % 1024;
        int co = r3 / 32, ci = r3 % 32;
        wr[base + r] = __float2bfloat16(w[n * 9216 + (co * 32 + ci) * 9 + tap]);
    } else if (idx < 2 * 27648 + 3 * 4608) {
        int r = idx - 2 * 27648;
        int n = r / 4608; int r2 = r % 4608;
        int tap = r2 / 512; int r3 = r2 % 512;
        int co = r3 / 32, ci = r3 % 32;
        float v = (co == 0) ? w4[n * 288 + ci * 9 + tap] : 0.f;
        wr[WR4_OFF + r] = __float2bfloat16(v);
    }
    if (idx < 2 * PIMG) {
        int b = idx / PIMG, p = idx % PIMG;
        int y = p / PW, x = p % PW;
        bool interior = (y >= 2 && y < 2 + NN && x >= 2 && x < 2 + NN);
        float v = interior ? x0[b * NN * NN + (y - 2) * NN + (x - 2)] : 0.f;
        ws[O_XP + idx] = v;
        if (!interior) {
            ws[O_YP + idx] = 0.f;
            ws[O_YPT + idx] = 0.f;
        }
    }
}

// intersect t-interval with constraint lo < A + tc*coef < hi, via inv = 1/coef
__device__ __forceinline__ void isect2(float A, float inv, float lo, float hi,
                                       float& tlo, float& thi)
{
    float a = (lo - A) * inv, b = (hi - A) * inv;
    tlo = fmaxf(tlo, fminf(a, b));   // NaN (0*inf) dropped by fmin/fmax -> safe
    thi = fminf(thi, fmaxf(a, b));
}

// ---- radon forward: TWO adjacent rays per wave, 32 t-lanes each ----
__global__ __launch_bounds__(256) void k_radon(const float* __restrict__ img,
    const float* __restrict__ imgT, const float* __restrict__ ws,
    float* __restrict__ out)
{
    int b = blockIdx.z, a = blockIdx.y;
    int wave = threadIdx.x >> 6;
    int lane = threadIdx.x & 63;
    int half = lane >> 5, tl = lane & 31;
    int s = blockIdx.x * 8 + wave * 2 + half;
    float cs = ws[O_CS + a], sn = ws[O_SN + a];
    float ics = ws[O_ICS + a], isn = ws[O_ISN + a];
    float s_c = (float)s - 364.0f;
    float A_r = 255.5f + s_c * sn;    // r(t) = A_r + tc*cs
    float A_c = 255.5f + s_c * cs;    // c(t) = A_c - tc*sn

    float tlo = -1e9f, thi = 1e9f;
    isect2(A_r, ics, -1.0f, 512.0f, tlo, thi);
    isect2(A_c, isn, -1.0f, 512.0f, tlo, thi);
    float t0f = fmaxf(tlo + 364.0f, 0.0f);
    float t1f = fminf(thi + 364.0f, 728.0f);

    bool useT = fabsf(cs) >= fabsf(sn);   // wave-uniform
    const float* im = (useT ? imgT : img) + b * PIMG;

    float acc = 0.f;
    if (s < ND && t0f <= t1f) {
        int tb = (int)ceilf(t0f);
        int te = (int)floorf(t1f);
#pragma unroll 2
        for (int t = tb + tl; t <= te; t += 32) {
            float tc = (float)t - 364.0f;
            float r = fmaf(tc, cs, A_r);
            float c = fmaf(-tc, sn, A_c);
            float rf = floorf(r), cf = floorf(c);
            float dr = r - rf, dc = c - cf;
            int irr = (int)rf, icc = (int)cf;
            int idx = useT ? (icc * PW + irr) : (irr * PW + icc);
            float da = useT ? dr : dc;
            float db = useT ? dc : dr;
            float2 p1 = ld2u(im + idx);
            float2 p2 = ld2u(im + idx + PW);
            float u = fmaf(da, p1.y - p1.x, p1.x);
            float w = fmaf(da, p2.y - p2.x, p2.x);
            acc = fmaf(db, w - u, acc + u);
        }
    }
    // butterfly within each 32-lane half (masks <= 16 never cross the half)
    acc += __shfl_xor(acc, 16, 64);
    acc += __shfl_xor(acc, 8, 64);
    acc += __shfl_xor(acc, 4, 64);
    acc += __shfl_xor(acc, 2, 64);
    acc += __shfl_xor(acc, 1, 64);
    if (tl == 0 && s < ND) out[(b * NA + a) * ND + s] = acc;
}

// ---- ramp filter as direct odd-tap convolution: q = sino - scale*conv(sp) ----
__global__ void k_filter(const float* __restrict__ sp, const float* __restrict__ sino,
                         float* __restrict__ q)
{
    __shared__ float row[ND];
    __shared__ float taps[364];
    int ba = blockIdx.y;
    const float* src = sp + ba * ND;
    for (int i = threadIdx.x; i < ND; i += 256) row[i] = src[i];
    const float PI2 = 9.86960440108936f;
    for (int i = threadIdx.x; i < 364; i += 256) {
        float m = (float)(2 * i + 1);
        taps[i] = -2.0f / (PI2 * m * m);
    }
    __syncthreads();
    const float scale = 0.0523598775598299f;  // pi/(2A)
    int d = blockIdx.x * 256 + threadIdx.x;
    if (d < ND) {
        float g0 = 0.5f * row[d], g1 = 0.f;
#pragma unroll 4
        for (int j = 0; j < 364; j += 2) {
            int m0 = 2 * j + 1, m1 = 2 * j + 3;
            float l0 = (d - m0 >= 0) ? row[d - m0] : 0.f;
            float r0 = (d + m0 < ND) ? row[d + m0] : 0.f;
            g0 = fmaf(taps[j], l0 + r0, g0);
            float l1 = (d - m1 >= 0) ? row[d - m1] : 0.f;
            float r1 = (d + m1 < ND) ? row[d + m1] : 0.f;
            g1 = fmaf(taps[j + 1], l1 + r1, g1);
        }
        q[ba * ND + d] = sino[ba * ND + d] - scale * (g0 + g1);
    }
}

// ---- LDS-tiled backprojection + update:  out = src1 + steps[n]*bp(q) ----
__global__ __launch_bounds__(256) void k_backproj_update(const float* __restrict__ q,
    const float* __restrict__ src1, const float* __restrict__ ws,
    const float* __restrict__ steps, int n, float* __restrict__ out,
    float* __restrict__ outcopy)
{
    __shared__ float qt[NA][28];
    __shared__ int dmin_s[NA];
    int b = blockIdx.z;
    int x0 = blockIdx.x * 16, y0 = blockIdx.y * 16;
    int tid = threadIdx.x;
    int lx = tid & 15, ly = tid >> 4;
    const float* qb = q + b * NA * ND;

    for (int idx = tid; idx < NA * 26; idx += 256) {
        int a = idx / 26, j = idx % 26;
        float cs = ws[O_CS + a], sn = ws[O_SN + a];
        float f00 = fmaf(cs, (float)x0 - 255.5f, fmaf(sn, (float)y0 - 255.5f, 364.0f));
        float fmn = f00 + fminf(cs * 15.f, 0.f) + fminf(sn * 15.f, 0.f);
        int dm = (int)floorf(fmn);
        if (j == 0) dmin_s[a] = dm;
        int d = dm + j;
        qt[a][j] = (d >= 0 && d < ND) ? qb[a * ND + d] : 0.f;
    }
    __syncthreads();

    float xc = (float)(x0 + lx) - 255.5f, yc = (float)(y0 + ly) - 255.5f;
    float acc = 0.f;
#pragma unroll
    for (int a = 0; a < NA; a++) {
        float cs = ws[O_CS + a], sn = ws[O_SN + a];
        float f = fmaf(cs, xc, fmaf(sn, yc, 364.0f));
        float lf = floorf(f);
        float w = f - lf;
        int j = (int)lf - dmin_s[a];
        float v0 = qt[a][j], v1 = qt[a][j + 1];
        acc = fmaf(v0, 1.0f - w, fmaf(v1, w, acc));
    }
    int pidx = b * PIMG + (y0 + ly) * PW + (x0 + lx);
    float v = fmaf(steps[n], acc, src1[pidx]);
    out[pidx] = v;
    if (outcopy) {
        int fidx = b * NN * NN + (y0 + ly) * NN + (x0 + lx);
        outcopy[fidx] = v;
        outcopy[fidx + BNN] = v;
        outcopy[fidx + 2 * BNN] = v;
    }
}

// ---- FUSED conv1+conv2: XP -> (h1 halo tile in LDS) -> h2 (HWC bf16 global) ----
__global__ __launch_bounds__(256) void k_conv12(const float* __restrict__ XPb,
    const float* __restrict__ W1, const float* __restrict__ B1,
    const bf16* __restrict__ Wr2, const float* __restrict__ B2,
    bf16* __restrict__ outb)
{
    __shared__ bf16 h1t[34][18][32];
    int b = blockIdx.z;
    int x0 = blockIdx.x * 16;
    int Y0 = blockIdx.y * 32;
    const float* in = XPb + b * PIMG;      // origin-adjusted padded

    // ---- phase A: h1 on halo [Y0-1, Y0+33) x [x0-1, x0+17) ----
    for (int p = threadIdx.x; p < 34 * 18; p += 256) {
        int yy = p / 18, xx = p % 18;
        int gy = Y0 + yy - 1, gx = x0 + xx - 1;
        if (gy < 0 || gy >= NN || gx < 0 || gx >= NN) {
#pragma unroll
            for (int g = 0; g < 4; g++)
                *(short8*)(&h1t[yy][xx][g * 8]) = short8{};
        } else {
            float v[9];
#pragma unroll
            for (int dy = 0; dy < 3; dy++)
#pragma unroll
                for (int dx = 0; dx < 3; dx++)
                    v[dy * 3 + dx] = in[(gy + dy - 1) * PW + (gx + dx - 1)];
#pragma unroll
            for (int g = 0; g < 4; g++) {
                short8 pk;
#pragma unroll
                for (int j = 0; j < 8; j++) {
                    int co = g * 8 + j;
                    float a = B1[co];
                    const float* w = W1 + co * 9;   // block-uniform -> s_load
#pragma unroll
                    for (int k = 0; k < 9; k++) a = fmaf(v[k], w[k], a);
                    a = fmaxf(a, 0.f);
                    bf16 h = __float2bfloat16(a);
                    pk[j] = *reinterpret_cast<short*>(&h);
                }
                *(short8*)(&h1t[yy][xx][g * 8]) = pk;
            }
        }
    }
    __syncthreads();

    // ---- phase B: conv2 (MFMA), h1 from LDS ----
    int lane = threadIdx.x & 63;
    int wave = threadIdx.x >> 6;
    int n16 = lane & 15, quad = lane >> 4;
    int y0w = Y0 + wave * 8;

    short8 wf[18];
#pragma unroll
    for (int tap = 0; tap < 9; tap++)
#pragma unroll
        for (int t = 0; t < 2; t++)
            wf[tap * 2 + t] = *(const short8*)(Wr2 + ((tap * 2 + t) * 16 + n16) * 32 + quad * 8);

    short8 win[3][3];
    auto loadrow = [&](int yy, short8* dst) {
        int ly = yy - (Y0 - 1);   // always in [0,34)
#pragma unroll
        for (int dx = 0; dx < 3; dx++)
            dst[dx] = *(const short8*)(&h1t[ly][n16 + dx][quad * 8]);
    };
    loadrow(y0w - 1, win[0]);
    loadrow(y0w,     win[1]);

    float4v bias[2];
#pragma unroll
    for (int t = 0; t < 2; t++)
        bias[t] = *(const float4v*)(B2 + t * 16 + quad * 4);

    bf16* out = outb + (size_t)b * NN * NN * 32;
#pragma unroll
    for (int i = 0; i < 8; i++) {
        int y = y0w + i;
        loadrow(y + 1, win[(i + 2) % 3]);
        float4v acc[2];
#pragma unroll
        for (int t = 0; t < 2; t++) acc[t] = bias[t];
#pragma unroll
        for (int dy = 0; dy < 3; dy++) {
            short8* row = win[(i + dy) % 3];
#pragma unroll
            for (int dx = 0; dx < 3; dx++) {
                int tap = dy * 3 + dx;
#pragma unroll
                for (int t = 0; t < 2; t++)
                    acc[t] = __builtin_amdgcn_mfma_f32_16x16x32_bf16(wf[tap * 2 + t], row[dx], acc[t], 0, 0, 0);
            }
        }
        bf16* pp = out + ((size_t)y * NN + x0 + n16) * 32 + quad * 4;
#pragma unroll
        for (int t = 0; t < 2; t++) {
            s4v pk;
#pragma unroll
            for (int r = 0; r < 4; r++) {
                float v = fmaxf(acc[t][r], 0.f);
                bf16 h = __float2bfloat16(v);
                pk[r] = *reinterpret_cast<short*>(&h);
            }
            *(s4v*)(pp + t * 16) = pk;
        }
    }
}

// ---- FUSED conv3+conv4, two-phase: h2 -> h3 tile in LDS -> YP/YPT ----
// 320 threads (5 waves). Phase 1: wave w = col-group w, rolling 4-row window
// (prefetch 1 row ahead of use: ~1 row of MFMAs between issue and first use).
// ONE barrier. Phase 2: waves 0-3 own 16-col out groups, LDS rolling window.
// YPT staged in LDS and written as coalesced 32B sectors.
#define C34_W 64
#define C34_H 8
#define C34_PX 66
#define H3S 36     // shorts per px (32 ch + 4 pad) -> 72 B: 16 distinct banks

__global__ __launch_bounds__(320, 3) void k_conv34(const bf16* __restrict__ inb,
    const bf16* __restrict__ Wr3, const float* __restrict__ B3,
    const bf16* __restrict__ Wr4, const float* __restrict__ addsrc,
    float* __restrict__ outY, float* __restrict__ outT)
{
    __shared__ bf16 h3s[10][C34_PX][H3S];
    __shared__ float otile[C34_W][10];   // [px][y] stride 40B, 8B-aligned rows
    int lane = threadIdx.x & 63;
    int wave = threadIdx.x >> 6;      // 0..4
    int n16 = lane & 15, quad = lane >> 4;
    int b = blockIdx.z;
    int x0 = blockIdx.x * C34_W;
    int y0 = blockIdx.y * C34_H;
    const bf16* in = inb + (size_t)b * NN * NN * 32;

    // ---- phase 1: conv3 for h3 rows y0-1..y0+8, cols x0-1..x0+64 ----
    {
        short8 wf3[18];
#pragma unroll
        for (int tap = 0; tap < 9; tap++)
#pragma unroll
            for (int t = 0; t < 2; t++)
                wf3[tap * 2 + t] = *(const short8*)(Wr3 + ((tap * 2 + t) * 16 + n16) * 32 + quad * 8);
        float4v bias3[2];
#pragma unroll
        for (int t = 0; t < 2; t++)
            bias3[t] = *(const float4v*)(B3 + t * 16 + quad * 4);

        int pxi = wave * 16 + n16;        // h3 col index, 0..79 (mask >= 66)
        int gx0 = x0 + pxi - 2;           // input col for dx=0
        bool cvx[3];
#pragma unroll
        for (int dx = 0; dx < 3; dx++) {
            int gx = gx0 + dx;
            cvx[dx] = (gx >= 0) && (gx < NN);
        }
        bool pxok = pxi < C34_PX;
        int gcol = x0 + pxi - 1;          // image col of this h3 col
        bool colv = pxok && (gcol >= 0) && (gcol < NN);

        // 4-slot rolling window: slot(row y0-2+k) = k & 3
        short8 win[4][3];
        auto ldrow = [&](int gy, short8* dst) {
            if (gy >= 0 && gy < NN) {
                const bf16* rowp = in + (size_t)gy * NN * 32 + quad * 8;
#pragma unroll
                for (int dx = 0; dx < 3; dx++) {
                    short8 v = {};
                    if (cvx[dx]) v = *(const short8*)(rowp + (size_t)(gx0 + dx) * 32);
                    dst[dx] = v;
                }
            } else {
                dst[0] = short8{}; dst[1] = short8{}; dst[2] = short8{};
            }
        };
        ldrow(y0 - 2, win[0]);
        ldrow(y0 - 1, win[1]);
        ldrow(y0,     win[2]);
#pragma unroll
        for (int r = 0; r < 10; r++) {
            int hy = y0 - 1 + r;
            if (r < 9) ldrow(y0 + r + 1, win[(r + 3) & 3]);   // prefetch 1 row ahead
            float4v a3[2] = {bias3[0], bias3[1]};
#pragma unroll
            for (int dy = 0; dy < 3; dy++) {
                short8* row = win[(r + dy) & 3];
#pragma unroll
                for (int dx = 0; dx < 3; dx++) {
                    int tap = dy * 3 + dx;
#pragma unroll
                    for (int t = 0; t < 2; t++)
                        a3[t] = __builtin_amdgcn_mfma_f32_16x16x32_bf16(wf3[tap * 2 + t], row[dx], a3[t], 0, 0, 0);
                }
            }
            bool rowv = (hy >= 0) && (hy < NN);
            bool live = rowv && colv;
            if (pxok) {
#pragma unroll
                for (int t = 0; t < 2; t++) {
                    s4v pk = {};
                    if (live) {
#pragma unroll
                        for (int r2 = 0; r2 < 4; r2++) {
                            float v = fmaxf(a3[t][r2], 0.f);
                            bf16 h = __float2bfloat16(v);
                            pk[r2] = *reinterpret_cast<short*>(&h);
                        }
                    }
                    *(s4v*)(&h3s[r][pxi][t * 16 + quad * 4]) = pk;
                }
            }
        }
    }
    __syncthreads();

    // ---- phase 2: conv4 from LDS, waves 0-3 ----
    if (wave < 4) {
        short8 wf4[9];
#pragma unroll
        for (int tap = 0; tap < 9; tap++)
            wf4[tap] = *(const short8*)(Wr4 + (tap * 16 + n16) * 32 + quad * 8);

        int c = wave * 16 + n16;          // local out col 0..63 -> h3 cols c..c+2
        short8 hw[3][3];
        auto ldh = [&](int r, short8* dst) {
#pragma unroll
            for (int dx = 0; dx < 3; dx++)
                dst[dx] = *(const short8*)(&h3s[r][c + dx][quad * 8]);
        };
        ldh(0, hw[0]);
        ldh(1, hw[1]);
#pragma unroll
        for (int i = 0; i < 8; i++) {
            ldh(i + 2, hw[(i + 2) % 3]);
            float4v a4 = {0.f, 0.f, 0.f, 0.f};
#pragma unroll
            for (int dy = 0; dy < 3; dy++) {
                short8* row = hw[(i + dy) % 3];
#pragma unroll
                for (int dx = 0; dx < 3; dx++)
                    a4 = __builtin_amdgcn_mfma_f32_16x16x32_bf16(wf4[dy * 3 + dx], row[dx], a4, 0, 0, 0);
            }
            if (quad == 0) {
                int px = x0 + c;
                int y = y0 + i;
                int pidx = b * PIMG + y * PW + px;
                float vv = addsrc[pidx] + a4[0];
                outY[pidx] = vv;
                otile[c][i] = vv;
            }
        }
    }
    __syncthreads();
    // ---- coalesced YPT store: 4 threads x float2 per transposed row ----
    if (threadIdx.x < 256) {
        int p = threadIdx.x >> 2;         // local px 0..63
        int yq = threadIdx.x & 3;         // pair index
        float2 v;
        v.x = otile[p][yq * 2];
        v.y = otile[p][yq * 2 + 1];
        float* dst = outT + b * PIMG + (size_t)(x0 + p) * PW + y0 + yq * 2;
        __builtin_memcpy(dst, &v, 8);
    }
}

extern "C" void kernel_launch(void* const* d_in, const int* in_sizes, int n_in,
                              void* d_out, int out_size, void* d_ws, size_t ws_size,
                              hipStream_t stream)
{
    const float* x0    = (const float*)d_in[1];
    const float* sg    = (const float*)d_in[2];
    const float* theta = (const float*)d_in[3];
    const float* w1    = (const float*)d_in[5];
    const float* b1    = (const float*)d_in[6];
    const float* w2    = (const float*)d_in[7];
    const float* b2    = (const float*)d_in[8];
    const float* w3    = (const float*)d_in[9];
    const float* b3    = (const float*)d_in[10];
    const float* w4    = (const float*)d_in[11];
    const float* steps = (const float*)d_in[12];

    float* ws = (float*)d_ws;
    float* XP  = ws + O_XP + POFF;    // origin-adjusted padded pointers
    float* YP  = ws + O_YP + POFF;
    float* YPT = ws + O_YPT + POFF;
    float* SP = ws + O_SP;
    float* Q  = ws + O_Q;
    bf16* wr  = (bf16*)(ws + O_WR);
    bf16* h2  = (bf16*)(ws + O_H + H_FLOATS);

    k_prep<<<(2 * PIMG + 255) / 256, 256, 0, stream>>>(theta, w2, w3, w4, x0, ws, wr);

    for (int n = 0; n < NL; n++) {
        // denoiser: fused conv1+2 (XP -> h2), fused conv3+4 (h2 -> YP/YPT)
        k_conv12<<<dim3(32, 16, NB), 256, 0, stream>>>(
            XP, w1 + n * 288, b1 + n * 32, wr + WR2_OFF + n * 9216, b2 + n * 32, h2);
        k_conv34<<<dim3(8, 64, NB), 320, 0, stream>>>(
            h2, wr + WR3_OFF + n * 9216, b3 + n * 32, wr + WR4_OFF + n * 4608,
            XP, YP, YPT);

        // fused physics path (linearity): XP = YP + steps[n]*bp(sino - F(R(YP)))
        k_radon<<<dim3((ND + 7) / 8, NA, NB), 256, 0, stream>>>(YP, YPT, ws, SP);
        k_filter<<<dim3(3, NB * NA), 256, 0, stream>>>(SP, sg, Q);
        k_backproj_update<<<dim3(32, 32, NB), 256, 0, stream>>>(
            Q, YP, ws, steps, n, XP, (n == NL - 1) ? (float*)d_out : nullptr);
    }
}

// Round 4
// 427.919 us; speedup vs baseline: 1.0183x; 1.0183x over previous
//
#include <hip/hip_runtime.h>
#include <hip/hip_bf16.h>

typedef __hip_bfloat16 bf16;
typedef __attribute__((ext_vector_type(8))) short short8;
typedef __attribute__((ext_vector_type(4))) short s4v;
typedef __attribute__((ext_vector_type(4))) float float4v;

#define NN 512      // image N
#define NA 30       // angles
#define ND 729      // detectors
#define NB 2        // batch
#define NL 3        // iterations
#define BNN (NB*NN*NN)     // 524288
#define BAD (NB*NA*ND)     // 43740

// padded image layout: PH x PW, logical (0,0) at physical (2,2)
#define PW 520
#define PH 516
#define PIMG (PH*PW)       // 268320
#define POFF (2*PW + 2)    // 1042

// ---- workspace float offsets ----
#define O_CS  0
#define O_SN  32
#define O_ICS 64                      // 1/cs per angle
#define O_ISN 96                      // -1/sn per angle
#define O_XP  128                     // 2*PIMG  (current X, padded)
#define O_YP  (O_XP + 2*PIMG)         // 2*PIMG  (Y = X + noise, padded)
#define O_YPT (O_YP + 2*PIMG)         // 2*PIMG  (transposed Y, padded)
#define O_SP  (O_YPT + 2*PIMG)        // BAD
#define O_Q   (O_SP + BAD)            // BAD
#define O_WR  (O_Q + BAD)             // bf16 region: 69120 bf16 = 34560 floats
#define O_H   (((O_WR + 34560) + 15) & ~15)
#define H_FLOATS (NB * 32 * NN * NN / 2)

// repacked weight bf16 offsets within WR region
#define WR2_OFF 0                   // [n][tap][co32][ci32] : 3*9216
#define WR3_OFF 27648               // 3*9216
#define WR4_OFF 55296               // [n][tap][co16][ci32] : 3*4608 (co>0 zero)

// unaligned 8B load (pair of adjacent floats) -> global_load_dwordx2
__device__ __forceinline__ float2 ld2u(const float* p)
{
    float2 r;
    __builtin_memcpy(&r, p, 8);
    return r;
}

// ---- setup: angles + reciprocals + weight repack + image padding, one kernel ----
__global__ void k_prep(const float* __restrict__ theta,
                       const float* __restrict__ w2, const float* __restrict__ w3,
                       const float* __restrict__ w4, const float* __restrict__ x0,
                       float* __restrict__ ws, bf16* __restrict__ wr)
{
    int idx = blockIdx.x * 256 + threadIdx.x;
    if (idx < NA) {
        float t = theta[idx];
        float cs = cosf(t), sn = sinf(t);
        ws[O_CS + idx] = cs;
        ws[O_SN + idx] = sn;
        ws[O_ICS + idx] = 1.0f / cs;      // +-inf ok
        ws[O_ISN + idx] = -1.0f / sn;     // +-inf ok
    }
    if (idx < 2 * 27648) {
        const float* w = (idx < 27648) ? w2 : w3;
        int base = (idx < 27648) ? WR2_OFF : WR3_OFF;
        int r = idx % 27648;
        int n = r / 9216; int r2 = r % 9216;
        int tap = r2 / 1024; int r3 = r2 % 1024;
        int co = r3 / 32, ci = r3 % 32;
        wr[base + r] = __float2bfloat16(w[n * 9216 + (co * 32 + ci) * 9 + tap]);
    } else if (idx < 2 * 27648 + 3 * 4608) {
        int r = idx - 2 * 27648;
        int n = r / 4608; int r2 = r % 4608;
        int tap = r2 / 512; int r3 = r2 % 512;
        int co = r3 / 32, ci = r3 % 32;
        float v = (co == 0) ? w4[n * 288 + ci * 9 + tap] : 0.f;
        wr[WR4_OFF + r] = __float2bfloat16(v);
    }
    if (idx < 2 * PIMG) {
        int b = idx / PIMG, p = idx % PIMG;
        int y = p / PW, x = p % PW;
        bool interior = (y >= 2 && y < 2 + NN && x >= 2 && x < 2 + NN);
        float v = interior ? x0[b * NN * NN + (y - 2) * NN + (x - 2)] : 0.f;
        ws[O_XP + idx] = v;
        if (!interior) {
            ws[O_YP + idx] = 0.f;
            ws[O_YPT + idx] = 0.f;
        }
    }
}

// intersect t-interval with constraint lo < A + tc*coef < hi, via inv = 1/coef
__device__ __forceinline__ void isect2(float A, float inv, float lo, float hi,
                                       float& tlo, float& thi)
{
    float a = (lo - A) * inv, b = (hi - A) * inv;
    tlo = fmaxf(tlo, fminf(a, b));   // NaN (0*inf) dropped by fmin/fmax -> safe
    thi = fminf(thi, fmaxf(a, b));
}

// ---- radon forward: TWO adjacent rays per wave, 32 t-lanes each ----
__global__ __launch_bounds__(256) void k_radon(const float* __restrict__ img,
    const float* __restrict__ imgT, const float* __restrict__ ws,
    float* __restrict__ out)
{
    int b = blockIdx.z, a = blockIdx.y;
    int wave = threadIdx.x >> 6;
    int lane = threadIdx.x & 63;
    int half = lane >> 5, tl = lane & 31;
    int s = blockIdx.x * 8 + wave * 2 + half;
    float cs = ws[O_CS + a], sn = ws[O_SN + a];
    float ics = ws[O_ICS + a], isn = ws[O_ISN + a];
    float s_c = (float)s - 364.0f;
    float A_r = 255.5f + s_c * sn;    // r(t) = A_r + tc*cs
    float A_c = 255.5f + s_c * cs;    // c(t) = A_c - tc*sn

    float tlo = -1e9f, thi = 1e9f;
    isect2(A_r, ics, -1.0f, 512.0f, tlo, thi);
    isect2(A_c, isn, -1.0f, 512.0f, tlo, thi);
    float t0f = fmaxf(tlo + 364.0f, 0.0f);
    float t1f = fminf(thi + 364.0f, 728.0f);

    bool useT = fabsf(cs) >= fabsf(sn);   // wave-uniform
    const float* im = (useT ? imgT : img) + b * PIMG;

    float acc = 0.f;
    if (s < ND && t0f <= t1f) {
        int tb = (int)ceilf(t0f);
        int te = (int)floorf(t1f);
#pragma unroll 2
        for (int t = tb + tl; t <= te; t += 32) {
            float tc = (float)t - 364.0f;
            float r = fmaf(tc, cs, A_r);
            float c = fmaf(-tc, sn, A_c);
            float rf = floorf(r), cf = floorf(c);
            float dr = r - rf, dc = c - cf;
            int irr = (int)rf, icc = (int)cf;
            int idx = useT ? (icc * PW + irr) : (irr * PW + icc);
            float da = useT ? dr : dc;
            float db = useT ? dc : dr;
            float2 p1 = ld2u(im + idx);
            float2 p2 = ld2u(im + idx + PW);
            float u = fmaf(da, p1.y - p1.x, p1.x);
            float w = fmaf(da, p2.y - p2.x, p2.x);
            acc = fmaf(db, w - u, acc + u);
        }
    }
    // butterfly within each 32-lane half (masks <= 16 never cross the half)
    acc += __shfl_xor(acc, 16, 64);
    acc += __shfl_xor(acc, 8, 64);
    acc += __shfl_xor(acc, 4, 64);
    acc += __shfl_xor(acc, 2, 64);
    acc += __shfl_xor(acc, 1, 64);
    if (tl == 0 && s < ND) out[(b * NA + a) * ND + s] = acc;
}

// ---- ramp filter as direct odd-tap convolution: q = sino - scale*conv(sp) ----
__global__ void k_filter(const float* __restrict__ sp, const float* __restrict__ sino,
                         float* __restrict__ q)
{
    __shared__ float row[ND];
    __shared__ float taps[364];
    int ba = blockIdx.y;
    const float* src = sp + ba * ND;
    for (int i = threadIdx.x; i < ND; i += 256) row[i] = src[i];
    const float PI2 = 9.86960440108936f;
    for (int i = threadIdx.x; i < 364; i += 256) {
        float m = (float)(2 * i + 1);
        taps[i] = -2.0f / (PI2 * m * m);
    }
    __syncthreads();
    const float scale = 0.0523598775598299f;  // pi/(2A)
    int d = blockIdx.x * 256 + threadIdx.x;
    if (d < ND) {
        float g0 = 0.5f * row[d], g1 = 0.f;
#pragma unroll 4
        for (int j = 0; j < 364; j += 2) {
            int m0 = 2 * j + 1, m1 = 2 * j + 3;
            float l0 = (d - m0 >= 0) ? row[d - m0] : 0.f;
            float r0 = (d + m0 < ND) ? row[d + m0] : 0.f;
            g0 = fmaf(taps[j], l0 + r0, g0);
            float l1 = (d - m1 >= 0) ? row[d - m1] : 0.f;
            float r1 = (d + m1 < ND) ? row[d + m1] : 0.f;
            g1 = fmaf(taps[j + 1], l1 + r1, g1);
        }
        q[ba * ND + d] = sino[ba * ND + d] - scale * (g0 + g1);
    }
}

// ---- LDS-tiled backprojection + update:  out = src1 + steps[n]*bp(q) ----
__global__ __launch_bounds__(256) void k_backproj_update(const float* __restrict__ q,
    const float* __restrict__ src1, const float* __restrict__ ws,
    const float* __restrict__ steps, int n, float* __restrict__ out,
    float* __restrict__ outcopy)
{
    __shared__ float qt[NA][28];
    __shared__ int dmin_s[NA];
    int b = blockIdx.z;
    int x0 = blockIdx.x * 16, y0 = blockIdx.y * 16;
    int tid = threadIdx.x;
    int lx = tid & 15, ly = tid >> 4;
    const float* qb = q + b * NA * ND;

    for (int idx = tid; idx < NA * 26; idx += 256) {
        int a = idx / 26, j = idx % 26;
        float cs = ws[O_CS + a], sn = ws[O_SN + a];
        float f00 = fmaf(cs, (float)x0 - 255.5f, fmaf(sn, (float)y0 - 255.5f, 364.0f));
        float fmn = f00 + fminf(cs * 15.f, 0.f) + fminf(sn * 15.f, 0.f);
        int dm = (int)floorf(fmn);
        if (j == 0) dmin_s[a] = dm;
        int d = dm + j;
        qt[a][j] = (d >= 0 && d < ND) ? qb[a * ND + d] : 0.f;
    }
    __syncthreads();

    float xc = (float)(x0 + lx) - 255.5f, yc = (float)(y0 + ly) - 255.5f;
    float acc = 0.f;
#pragma unroll
    for (int a = 0; a < NA; a++) {
        float cs = ws[O_CS + a], sn = ws[O_SN + a];
        float f = fmaf(cs, xc, fmaf(sn, yc, 364.0f));
        float lf = floorf(f);
        float w = f - lf;
        int j = (int)lf - dmin_s[a];
        float v0 = qt[a][j], v1 = qt[a][j + 1];
        acc = fmaf(v0, 1.0f - w, fmaf(v1, w, acc));
    }
    int pidx = b * PIMG + (y0 + ly) * PW + (x0 + lx);
    float v = fmaf(steps[n], acc, src1[pidx]);
    out[pidx] = v;
    if (outcopy) {
        int fidx = b * NN * NN + (y0 + ly) * NN + (x0 + lx);
        outcopy[fidx] = v;
        outcopy[fidx + BNN] = v;
        outcopy[fidx + 2 * BNN] = v;
    }
}

// ---- FUSED conv1+conv2: XP -> (h1 halo tile in LDS) -> h2 (HWC bf16 global) ----
__global__ __launch_bounds__(256) void k_conv12(const float* __restrict__ XPb,
    const float* __restrict__ W1, const float* __restrict__ B1,
    const bf16* __restrict__ Wr2, const float* __restrict__ B2,
    bf16* __restrict__ outb)
{
    __shared__ bf16 h1t[34][18][32];
    int b = blockIdx.z;
    int x0 = blockIdx.x * 16;
    int Y0 = blockIdx.y * 32;
    const float* in = XPb + b * PIMG;      // origin-adjusted padded

    // ---- phase A: h1 on halo [Y0-1, Y0+33) x [x0-1, x0+17) ----
    for (int p = threadIdx.x; p < 34 * 18; p += 256) {
        int yy = p / 18, xx = p % 18;
        int gy = Y0 + yy - 1, gx = x0 + xx - 1;
        if (gy < 0 || gy >= NN || gx < 0 || gx >= NN) {
#pragma unroll
            for (int g = 0; g < 4; g++)
                *(short8*)(&h1t[yy][xx][g * 8]) = short8{};
        } else {
            float v[9];
#pragma unroll
            for (int dy = 0; dy < 3; dy++)
#pragma unroll
                for (int dx = 0; dx < 3; dx++)
                    v[dy * 3 + dx] = in[(gy + dy - 1) * PW + (gx + dx - 1)];
#pragma unroll
            for (int g = 0; g < 4; g++) {
                short8 pk;
#pragma unroll
                for (int j = 0; j < 8; j++) {
                    int co = g * 8 + j;
                    float a = B1[co];
                    const float* w = W1 + co * 9;   // block-uniform -> s_load
#pragma unroll
                    for (int k = 0; k < 9; k++) a = fmaf(v[k], w[k], a);
                    a = fmaxf(a, 0.f);
                    bf16 h = __float2bfloat16(a);
                    pk[j] = *reinterpret_cast<short*>(&h);
                }
                *(short8*)(&h1t[yy][xx][g * 8]) = pk;
            }
        }
    }
    __syncthreads();

    // ---- phase B: conv2 (MFMA), h1 from LDS ----
    int lane = threadIdx.x & 63;
    int wave = threadIdx.x >> 6;
    int n16 = lane & 15, quad = lane >> 4;
    int y0w = Y0 + wave * 8;

    short8 wf[18];
#pragma unroll
    for (int tap = 0; tap < 9; tap++)
#pragma unroll
        for (int t = 0; t < 2; t++)
            wf[tap * 2 + t] = *(const short8*)(Wr2 + ((tap * 2 + t) * 16 + n16) * 32 + quad * 8);

    short8 win[3][3];
    auto loadrow = [&](int yy, short8* dst) {
        int ly = yy - (Y0 - 1);   // always in [0,34)
#pragma unroll
        for (int dx = 0; dx < 3; dx++)
            dst[dx] = *(const short8*)(&h1t[ly][n16 + dx][quad * 8]);
    };
    loadrow(y0w - 1, win[0]);
    loadrow(y0w,     win[1]);

    float4v bias[2];
#pragma unroll
    for (int t = 0; t < 2; t++)
        bias[t] = *(const float4v*)(B2 + t * 16 + quad * 4);

    bf16* out = outb + (size_t)b * NN * NN * 32;
#pragma unroll
    for (int i = 0; i < 8; i++) {
        int y = y0w + i;
        loadrow(y + 1, win[(i + 2) % 3]);
        float4v acc[2];
#pragma unroll
        for (int t = 0; t < 2; t++) acc[t] = bias[t];
#pragma unroll
        for (int dy = 0; dy < 3; dy++) {
            short8* row = win[(i + dy) % 3];
#pragma unroll
            for (int dx = 0; dx < 3; dx++) {
                int tap = dy * 3 + dx;
#pragma unroll
                for (int t = 0; t < 2; t++)
                    acc[t] = __builtin_amdgcn_mfma_f32_16x16x32_bf16(wf[tap * 2 + t], row[dx], acc[t], 0, 0, 0);
            }
        }
        bf16* pp = out + ((size_t)y * NN + x0 + n16) * 32 + quad * 4;
#pragma unroll
        for (int t = 0; t < 2; t++) {
            s4v pk;
#pragma unroll
            for (int r = 0; r < 4; r++) {
                float v = fmaxf(acc[t][r], 0.f);
                bf16 h = __float2bfloat16(v);
                pk[r] = *reinterpret_cast<short*>(&h);
            }
            *(s4v*)(pp + t * 16) = pk;
        }
    }
}

// ---- FUSED conv3+conv4, two-phase, 640 threads (10 waves) ----
// Phase 1: 5 col-groups x 2 row-halves; each wave computes 5 h3 rows with a
// rolling 3-slot window (r2-exact schedule, rows split for 2x wave-parallelism;
// +2 overlap halo input rows). ONE barrier. Phase 2: 4 col-groups x 2 row-
// halves; each wave does 4 output rows from LDS. YPT direct scatter (r2-exact).
#define C34_W 64
#define C34_H 8
#define C34_PX 66
#define H3S 40     // shorts per px (32 ch + 8 pad) -> 80 B stride

__global__ __launch_bounds__(640) void k_conv34(const bf16* __restrict__ inb,
    const bf16* __restrict__ Wr3, const float* __restrict__ B3,
    const bf16* __restrict__ Wr4, const float* __restrict__ addsrc,
    float* __restrict__ outY, float* __restrict__ outT)
{
    __shared__ bf16 h3s[10][C34_PX][H3S];
    int lane = threadIdx.x & 63;
    int wave = threadIdx.x >> 6;      // 0..9
    int n16 = lane & 15, quad = lane >> 4;
    int b = blockIdx.z;
    int x0 = blockIdx.x * C34_W;
    int y0 = blockIdx.y * C34_H;
    const bf16* in = inb + (size_t)b * NN * NN * 32;

    // ---- phase 1: conv3 for h3 rows y0-1..y0+8 (5 rows per wave) ----
    {
        int cg = wave % 5;                // col-group 0..4
        int rh = wave / 5;                // row-half 0..1
        short8 wf3[18];
#pragma unroll
        for (int tap = 0; tap < 9; tap++)
#pragma unroll
            for (int t = 0; t < 2; t++)
                wf3[tap * 2 + t] = *(const short8*)(Wr3 + ((tap * 2 + t) * 16 + n16) * 32 + quad * 8);
        float4v bias3[2];
#pragma unroll
        for (int t = 0; t < 2; t++)
            bias3[t] = *(const float4v*)(B3 + t * 16 + quad * 4);

        int pxi = cg * 16 + n16;          // h3 col index, 0..79 (mask >= 66)
        int gx0 = x0 + pxi - 2;           // input col for dx=0
        bool cvx[3];
#pragma unroll
        for (int dx = 0; dx < 3; dx++) {
            int gx = gx0 + dx;
            cvx[dx] = (gx >= 0) && (gx < NN);
        }
        bool pxok = pxi < C34_PX;
        int gcol = x0 + pxi - 1;          // image col of this h3 col
        bool colv = pxok && (gcol >= 0) && (gcol < NN);

        short8 win[3][3];
        auto ldrow = [&](int gy, short8* dst) {
            if (gy >= 0 && gy < NN) {
                const bf16* rowp = in + (size_t)gy * NN * 32 + quad * 8;
#pragma unroll
                for (int dx = 0; dx < 3; dx++) {
                    short8 v = {};
                    if (cvx[dx]) v = *(const short8*)(rowp + (size_t)(gx0 + dx) * 32);
                    dst[dx] = v;
                }
            } else {
                dst[0] = short8{}; dst[1] = short8{}; dst[2] = short8{};
            }
        };
        int hybase = y0 - 1 + rh * 5;     // first h3 row this wave produces
        ldrow(hybase - 1, win[0]);
        ldrow(hybase,     win[1]);
#pragma unroll
        for (int k = 0; k < 5; k++) {
            int hy = hybase + k;
            ldrow(hy + 1, win[(k + 2) % 3]);
            float4v a3[2] = {bias3[0], bias3[1]};
#pragma unroll
            for (int dy = 0; dy < 3; dy++) {
                short8* row = win[(k + dy) % 3];
#pragma unroll
                for (int dx = 0; dx < 3; dx++) {
                    int tap = dy * 3 + dx;
#pragma unroll
                    for (int t = 0; t < 2; t++)
                        a3[t] = __builtin_amdgcn_mfma_f32_16x16x32_bf16(wf3[tap * 2 + t], row[dx], a3[t], 0, 0, 0);
                }
            }
            bool rowv = (hy >= 0) && (hy < NN);
            bool live = rowv && colv;
            if (pxok) {
#pragma unroll
                for (int t = 0; t < 2; t++) {
                    s4v pk = {};
                    if (live) {
#pragma unroll
                        for (int r2 = 0; r2 < 4; r2++) {
                            float v = fmaxf(a3[t][r2], 0.f);
                            bf16 h = __float2bfloat16(v);
                            pk[r2] = *reinterpret_cast<short*>(&h);
                        }
                    }
                    *(s4v*)(&h3s[rh * 5 + k][pxi][t * 16 + quad * 4]) = pk;
                }
            }
        }
    }
    __syncthreads();

    // ---- phase 2: conv4 from LDS, waves 0-7 (4 rows per wave) ----
    if (wave < 8) {
        int cg2 = wave & 3;               // col-group 0..3
        int rh2 = wave >> 2;              // row-half 0..1
        short8 wf4[9];
#pragma unroll
        for (int tap = 0; tap < 9; tap++)
            wf4[tap] = *(const short8*)(Wr4 + (tap * 16 + n16) * 32 + quad * 8);

        int c = cg2 * 16 + n16;           // local out col 0..63 -> h3 cols c..c+2
        int i0 = rh2 * 4;                 // first output row this wave produces
        short8 hw[3][3];
        auto ldh = [&](int r, short8* dst) {
#pragma unroll
            for (int dx = 0; dx < 3; dx++)
                dst[dx] = *(const short8*)(&h3s[r][c + dx][quad * 8]);
        };
        ldh(i0,     hw[0]);
        ldh(i0 + 1, hw[1]);
#pragma unroll
        for (int k = 0; k < 4; k++) {
            ldh(i0 + k + 2, hw[(k + 2) % 3]);
            float4v a4 = {0.f, 0.f, 0.f, 0.f};
#pragma unroll
            for (int dy = 0; dy < 3; dy++) {
                short8* row = hw[(k + dy) % 3];
#pragma unroll
                for (int dx = 0; dx < 3; dx++)
                    a4 = __builtin_amdgcn_mfma_f32_16x16x32_bf16(wf4[dy * 3 + dx], row[dx], a4, 0, 0, 0);
            }
            if (quad == 0) {
                int px = x0 + c;
                int y = y0 + i0 + k;
                int pidx = b * PIMG + y * PW + px;
                float vv = addsrc[pidx] + a4[0];
                outY[pidx] = vv;
                outT[b * PIMG + px * PW + y] = vv;
            }
        }
    }
}

extern "C" void kernel_launch(void* const* d_in, const int* in_sizes, int n_in,
                              void* d_out, int out_size, void* d_ws, size_t ws_size,
                              hipStream_t stream)
{
    const float* x0    = (const float*)d_in[1];
    const float* sg    = (const float*)d_in[2];
    const float* theta = (const float*)d_in[3];
    const float* w1    = (const float*)d_in[5];
    const float* b1    = (const float*)d_in[6];
    const float* w2    = (const float*)d_in[7];
    const float* b2    = (const float*)d_in[8];
    const float* w3    = (const float*)d_in[9];
    const float* b3    = (const float*)d_in[10];
    const float* w4    = (const float*)d_in[11];
    const float* steps = (const float*)d_in[12];

    float* ws = (float*)d_ws;
    float* XP  = ws + O_XP + POFF;    // origin-adjusted padded pointers
    float* YP  = ws + O_YP + POFF;
    float* YPT = ws + O_YPT + POFF;
    float* SP = ws + O_SP;
    float* Q  = ws + O_Q;
    bf16* wr  = (bf16*)(ws + O_WR);
    bf16* h2  = (bf16*)(ws + O_H + H_FLOATS);

    k_prep<<<(2 * PIMG + 255) / 256, 256, 0, stream>>>(theta, w2, w3, w4, x0, ws, wr);

    for (int n = 0; n < NL; n++) {
        // denoiser: fused conv1+2 (XP -> h2), fused conv3+4 (h2 -> YP/YPT)
        k_conv12<<<dim3(32, 16, NB), 256, 0, stream>>>(
            XP, w1 + n * 288, b1 + n * 32, wr + WR2_OFF + n * 9216, b2 + n * 32, h2);
        k_conv34<<<dim3(8, 64, NB), 640, 0, stream>>>(
            h2, wr + WR3_OFF + n * 9216, b3 + n * 32, wr + WR4_OFF + n * 4608,
            XP, YP, YPT);

        // fused physics path (linearity): XP = YP + steps[n]*bp(sino - F(R(YP)))
        k_radon<<<dim3((ND + 7) / 8, NA, NB), 256, 0, stream>>>(YP, YPT, ws, SP);
        k_filter<<<dim3(3, NB * NA), 256, 0, stream>>>(SP, sg, Q);
        k_backproj_update<<<dim3(32, 32, NB), 256, 0, stream>>>(
            Q, YP, ws, steps, n, XP, (n == NL - 1) ? (float*)d_out : nullptr);
    }
}

// Round 5
// 422.842 us; speedup vs baseline: 1.0305x; 1.0120x over previous
//
#include <hip/hip_runtime.h>
#include <hip/hip_bf16.h>

typedef __hip_bfloat16 bf16;
typedef __attribute__((ext_vector_type(8))) short short8;
typedef __attribute__((ext_vector_type(4))) short s4v;
typedef __attribute__((ext_vector_type(4))) float float4v;
typedef __attribute__((ext_vector_type(4))) int int4v;

#define NN 512      // image N
#define NA 30       // angles
#define ND 729      // detectors
#define NB 2        // batch
#define NL 3        // iterations
#define BNN (NB*NN*NN)     // 524288
#define BAD (NB*NA*ND)     // 43740

// padded image layout: PH x PW, logical (0,0) at physical (2,2)
#define PW 520
#define PH 516
#define PIMG (PH*PW)       // 268320
#define POFF (2*PW + 2)    // 1042

// ---- workspace float offsets ----
#define O_CS  0
#define O_SN  32
#define O_ICS 64                      // 1/cs per angle
#define O_ISN 96                      // -1/sn per angle
#define O_XP  128                     // 2*PIMG  (current X, padded)
#define O_YP  (O_XP + 2*PIMG)         // 2*PIMG  (Y = X + noise, padded)
#define O_YPT (O_YP + 2*PIMG)         // 2*PIMG  (transposed Y, padded)
#define O_SP  (O_YPT + 2*PIMG)        // BAD
#define O_Q   (O_SP + BAD)            // BAD
#define O_WR  (O_Q + BAD)             // bf16 region: 69120 bf16 = 34560 floats
#define O_H   (((O_WR + 34560) + 15) & ~15)
#define H_FLOATS (NB * 32 * NN * NN / 2)

// repacked weight bf16 offsets within WR region
#define WR2_OFF 0                   // [n][tap][co32][ci32] : 3*9216
#define WR3_OFF 27648               // 3*9216
#define WR4_OFF 55296               // [n][tap][co16][ci32] : 3*4608 (co>0 zero)

// unaligned 8B load (pair of adjacent floats) -> global_load_dwordx2
__device__ __forceinline__ float2 ld2u(const float* p)
{
    float2 r;
    __builtin_memcpy(&r, p, 8);
    return r;
}

// pack two f32 -> one u32 of 2 bf16 (lo = x, hi = y)
__device__ __forceinline__ unsigned pk2(float x, float y)
{
    bf16 a = __float2bfloat16(x);
    bf16 b = __float2bfloat16(y);
    return (unsigned)*reinterpret_cast<unsigned short*>(&a)
         | ((unsigned)*reinterpret_cast<unsigned short*>(&b) << 16);
}

// ---- setup: angles + reciprocals + weight repack + image padding, one kernel ----
__global__ void k_prep(const float* __restrict__ theta,
                       const float* __restrict__ w2, const float* __restrict__ w3,
                       const float* __restrict__ w4, const float* __restrict__ x0,
                       float* __restrict__ ws, bf16* __restrict__ wr)
{
    int idx = blockIdx.x * 256 + threadIdx.x;
    if (idx < NA) {
        float t = theta[idx];
        float cs = cosf(t), sn = sinf(t);
        ws[O_CS + idx] = cs;
        ws[O_SN + idx] = sn;
        ws[O_ICS + idx] = 1.0f / cs;      // +-inf ok
        ws[O_ISN + idx] = -1.0f / sn;     // +-inf ok
    }
    if (idx < 2 * 27648) {
        const float* w = (idx < 27648) ? w2 : w3;
        int base = (idx < 27648) ? WR2_OFF : WR3_OFF;
        int r = idx % 27648;
        int n = r / 9216; int r2 = r % 9216;
        int tap = r2 / 1024; int r3 = r2 % 1024;
        int co = r3 / 32, ci = r3 % 32;
        wr[base + r] = __float2bfloat16(w[n * 9216 + (co * 32 + ci) * 9 + tap]);
    } else if (idx < 2 * 27648 + 3 * 4608) {
        int r = idx - 2 * 27648;
        int n = r / 4608; int r2 = r % 4608;
        int tap = r2 / 512; int r3 = r2 % 512;
        int co = r3 / 32, ci = r3 % 32;
        float v = (co == 0) ? w4[n * 288 + ci * 9 + tap] : 0.f;
        wr[WR4_OFF + r] = __float2bfloat16(v);
    }
    if (idx < 2 * PIMG) {
        int b = idx / PIMG, p = idx % PIMG;
        int y = p / PW, x = p % PW;
        bool interior = (y >= 2 && y < 2 + NN && x >= 2 && x < 2 + NN);
        float v = interior ? x0[b * NN * NN + (y - 2) * NN + (x - 2)] : 0.f;
        ws[O_XP + idx] = v;
        if (!interior) {
            ws[O_YP + idx] = 0.f;
            ws[O_YPT + idx] = 0.f;
        }
    }
}

// intersect t-interval with constraint lo < A + tc*coef < hi, via inv = 1/coef
__device__ __forceinline__ void isect2(float A, float inv, float lo, float hi,
                                       float& tlo, float& thi)
{
    float a = (lo - A) * inv, b = (hi - A) * inv;
    tlo = fmaxf(tlo, fminf(a, b));   // NaN (0*inf) dropped by fmin/fmax -> safe
    thi = fminf(thi, fmaxf(a, b));
}

// ---- radon forward: TWO adjacent rays per wave, 32 t-lanes each ----
__global__ __launch_bounds__(256) void k_radon(const float* __restrict__ img,
    const float* __restrict__ imgT, const float* __restrict__ ws,
    float* __restrict__ out)
{
    int b = blockIdx.z, a = blockIdx.y;
    int wave = threadIdx.x >> 6;
    int lane = threadIdx.x & 63;
    int half = lane >> 5, tl = lane & 31;
    int s = blockIdx.x * 8 + wave * 2 + half;
    float cs = ws[O_CS + a], sn = ws[O_SN + a];
    float ics = ws[O_ICS + a], isn = ws[O_ISN + a];
    float s_c = (float)s - 364.0f;
    float A_r = 255.5f + s_c * sn;    // r(t) = A_r + tc*cs
    float A_c = 255.5f + s_c * cs;    // c(t) = A_c - tc*sn

    float tlo = -1e9f, thi = 1e9f;
    isect2(A_r, ics, -1.0f, 512.0f, tlo, thi);
    isect2(A_c, isn, -1.0f, 512.0f, tlo, thi);
    float t0f = fmaxf(tlo + 364.0f, 0.0f);
    float t1f = fminf(thi + 364.0f, 728.0f);

    bool useT = fabsf(cs) >= fabsf(sn);   // wave-uniform
    const float* im = (useT ? imgT : img) + b * PIMG;

    float acc = 0.f;
    if (s < ND && t0f <= t1f) {
        int tb = (int)ceilf(t0f);
        int te = (int)floorf(t1f);
#pragma unroll 2
        for (int t = tb + tl; t <= te; t += 32) {
            float tc = (float)t - 364.0f;
            float r = fmaf(tc, cs, A_r);
            float c = fmaf(-tc, sn, A_c);
            float rf = floorf(r), cf = floorf(c);
            float dr = r - rf, dc = c - cf;
            int irr = (int)rf, icc = (int)cf;
            int idx = useT ? (icc * PW + irr) : (irr * PW + icc);
            float da = useT ? dr : dc;
            float db = useT ? dc : dr;
            float2 p1 = ld2u(im + idx);
            float2 p2 = ld2u(im + idx + PW);
            float u = fmaf(da, p1.y - p1.x, p1.x);
            float w = fmaf(da, p2.y - p2.x, p2.x);
            acc = fmaf(db, w - u, acc + u);
        }
    }
    // butterfly within each 32-lane half (masks <= 16 never cross the half)
    acc += __shfl_xor(acc, 16, 64);
    acc += __shfl_xor(acc, 8, 64);
    acc += __shfl_xor(acc, 4, 64);
    acc += __shfl_xor(acc, 2, 64);
    acc += __shfl_xor(acc, 1, 64);
    if (tl == 0 && s < ND) out[(b * NA + a) * ND + s] = acc;
}

// ---- ramp filter as direct odd-tap convolution: q = sino - scale*conv(sp) ----
__global__ void k_filter(const float* __restrict__ sp, const float* __restrict__ sino,
                         float* __restrict__ q)
{
    __shared__ float row[ND];
    __shared__ float taps[364];
    int ba = blockIdx.y;
    const float* src = sp + ba * ND;
    for (int i = threadIdx.x; i < ND; i += 256) row[i] = src[i];
    const float PI2 = 9.86960440108936f;
    for (int i = threadIdx.x; i < 364; i += 256) {
        float m = (float)(2 * i + 1);
        taps[i] = -2.0f / (PI2 * m * m);
    }
    __syncthreads();
    const float scale = 0.0523598775598299f;  // pi/(2A)
    int d = blockIdx.x * 256 + threadIdx.x;
    if (d < ND) {
        float g0 = 0.5f * row[d], g1 = 0.f;
#pragma unroll 4
        for (int j = 0; j < 364; j += 2) {
            int m0 = 2 * j + 1, m1 = 2 * j + 3;
            float l0 = (d - m0 >= 0) ? row[d - m0] : 0.f;
            float r0 = (d + m0 < ND) ? row[d + m0] : 0.f;
            g0 = fmaf(taps[j], l0 + r0, g0);
            float l1 = (d - m1 >= 0) ? row[d - m1] : 0.f;
            float r1 = (d + m1 < ND) ? row[d + m1] : 0.f;
            g1 = fmaf(taps[j + 1], l1 + r1, g1);
        }
        q[ba * ND + d] = sino[ba * ND + d] - scale * (g0 + g1);
    }
}

// ---- LDS-tiled backprojection + update:  out = src1 + steps[n]*bp(q) ----
__global__ __launch_bounds__(256) void k_backproj_update(const float* __restrict__ q,
    const float* __restrict__ src1, const float* __restrict__ ws,
    const float* __restrict__ steps, int n, float* __restrict__ out,
    float* __restrict__ outcopy)
{
    __shared__ float qt[NA][28];
    __shared__ int dmin_s[NA];
    int b = blockIdx.z;
    int x0 = blockIdx.x * 16, y0 = blockIdx.y * 16;
    int tid = threadIdx.x;
    int lx = tid & 15, ly = tid >> 4;
    const float* qb = q + b * NA * ND;

    for (int idx = tid; idx < NA * 26; idx += 256) {
        int a = idx / 26, j = idx % 26;
        float cs = ws[O_CS + a], sn = ws[O_SN + a];
        float f00 = fmaf(cs, (float)x0 - 255.5f, fmaf(sn, (float)y0 - 255.5f, 364.0f));
        float fmn = f00 + fminf(cs * 15.f, 0.f) + fminf(sn * 15.f, 0.f);
        int dm = (int)floorf(fmn);
        if (j == 0) dmin_s[a] = dm;
        int d = dm + j;
        qt[a][j] = (d >= 0 && d < ND) ? qb[a * ND + d] : 0.f;
    }
    __syncthreads();

    float xc = (float)(x0 + lx) - 255.5f, yc = (float)(y0 + ly) - 255.5f;
    float acc = 0.f;
#pragma unroll
    for (int a = 0; a < NA; a++) {
        float cs = ws[O_CS + a], sn = ws[O_SN + a];
        float f = fmaf(cs, xc, fmaf(sn, yc, 364.0f));
        float lf = floorf(f);
        float w = f - lf;
        int j = (int)lf - dmin_s[a];
        float v0 = qt[a][j], v1 = qt[a][j + 1];
        acc = fmaf(v0, 1.0f - w, fmaf(v1, w, acc));
    }
    int pidx = b * PIMG + (y0 + ly) * PW + (x0 + lx);
    float v = fmaf(steps[n], acc, src1[pidx]);
    out[pidx] = v;
    if (outcopy) {
        int fidx = b * NN * NN + (y0 + ly) * NN + (x0 + lx);
        outcopy[fidx] = v;
        outcopy[fidx + BNN] = v;
        outcopy[fidx + 2 * BNN] = v;
    }
}

// ---- FUSED conv1+conv2: XP -> (h1 halo tile in LDS) -> h2 (HWC bf16 global) ----
__global__ __launch_bounds__(256) void k_conv12(const float* __restrict__ XPb,
    const float* __restrict__ W1, const float* __restrict__ B1,
    const bf16* __restrict__ Wr2, const float* __restrict__ B2,
    bf16* __restrict__ outb)
{
    __shared__ bf16 h1t[34][18][32];
    int b = blockIdx.z;
    int x0 = blockIdx.x * 16;
    int Y0 = blockIdx.y * 32;
    const float* in = XPb + b * PIMG;      // origin-adjusted padded

    // ---- phase A: h1 on halo [Y0-1, Y0+33) x [x0-1, x0+17) ----
    for (int p = threadIdx.x; p < 34 * 18; p += 256) {
        int yy = p / 18, xx = p % 18;
        int gy = Y0 + yy - 1, gx = x0 + xx - 1;
        if (gy < 0 || gy >= NN || gx < 0 || gx >= NN) {
#pragma unroll
            for (int g = 0; g < 4; g++)
                *(short8*)(&h1t[yy][xx][g * 8]) = short8{};
        } else {
            float v[9];
#pragma unroll
            for (int dy = 0; dy < 3; dy++)
#pragma unroll
                for (int dx = 0; dx < 3; dx++)
                    v[dy * 3 + dx] = in[(gy + dy - 1) * PW + (gx + dx - 1)];
#pragma unroll
            for (int g = 0; g < 4; g++) {
                short8 pk;
#pragma unroll
                for (int j = 0; j < 8; j++) {
                    int co = g * 8 + j;
                    float a = B1[co];
                    const float* w = W1 + co * 9;   // block-uniform -> s_load
#pragma unroll
                    for (int k = 0; k < 9; k++) a = fmaf(v[k], w[k], a);
                    a = fmaxf(a, 0.f);
                    bf16 h = __float2bfloat16(a);
                    pk[j] = *reinterpret_cast<short*>(&h);
                }
                *(short8*)(&h1t[yy][xx][g * 8]) = pk;
            }
        }
    }
    __syncthreads();

    // ---- phase B: conv2 (MFMA), h1 from LDS ----
    int lane = threadIdx.x & 63;
    int wave = threadIdx.x >> 6;
    int n16 = lane & 15, quad = lane >> 4;
    int y0w = Y0 + wave * 8;

    short8 wf[18];
#pragma unroll
    for (int tap = 0; tap < 9; tap++)
#pragma unroll
        for (int t = 0; t < 2; t++)
            wf[tap * 2 + t] = *(const short8*)(Wr2 + ((tap * 2 + t) * 16 + n16) * 32 + quad * 8);

    short8 win[3][3];
    auto loadrow = [&](int yy, short8* dst) {
        int ly = yy - (Y0 - 1);   // always in [0,34)
#pragma unroll
        for (int dx = 0; dx < 3; dx++)
            dst[dx] = *(const short8*)(&h1t[ly][n16 + dx][quad * 8]);
    };
    loadrow(y0w - 1, win[0]);
    loadrow(y0w,     win[1]);

    float4v bias[2];
#pragma unroll
    for (int t = 0; t < 2; t++)
        bias[t] = *(const float4v*)(B2 + t * 16 + quad * 4);

    bf16* out = outb + (size_t)b * NN * NN * 32;
#pragma unroll
    for (int i = 0; i < 8; i++) {
        int y = y0w + i;
        loadrow(y + 1, win[(i + 2) % 3]);
        float4v acc[2];
#pragma unroll
        for (int t = 0; t < 2; t++) acc[t] = bias[t];
#pragma unroll
        for (int dy = 0; dy < 3; dy++) {
            short8* row = win[(i + dy) % 3];
#pragma unroll
            for (int dx = 0; dx < 3; dx++) {
                int tap = dy * 3 + dx;
#pragma unroll
                for (int t = 0; t < 2; t++)
                    acc[t] = __builtin_amdgcn_mfma_f32_16x16x32_bf16(wf[tap * 2 + t], row[dx], acc[t], 0, 0, 0);
            }
        }
        bf16* pp = out + ((size_t)y * NN + x0 + n16) * 32 + quad * 4;
#pragma unroll
        for (int t = 0; t < 2; t++) {
            s4v pk;
#pragma unroll
            for (int r = 0; r < 4; r++) {
                float v = fmaxf(acc[t][r], 0.f);
                bf16 h = __float2bfloat16(v);
                pk[r] = *reinterpret_cast<short*>(&h);
            }
            *(s4v*)(pp + t * 16) = pk;
        }
    }
}

// ---- FUSED conv3+conv4, FULLY IN-REGISTER (no LDS, no barrier) ----
// Each wave owns a 16-px strip (valid out = middle 14, overlap-discard) and
// streams 8 output rows. Per h3 row: conv3 (18 K32 MFMA) -> C-frag
// (px=lane&15, co=quad*4+reg) repacked to conv4 B-frag (px=lane&15,
// ci=quad*8+j) via 4 pk2 + 8 ds_bpermute + 4 selects. conv4 = 9 K32 MFMA
// into 3 dx-accumulators, combined by two lane shifts at the end.
__global__ __launch_bounds__(256) void k_conv34(const bf16* __restrict__ inb,
    const bf16* __restrict__ Wr3, const float* __restrict__ B3,
    const bf16* __restrict__ Wr4, const float* __restrict__ addsrc,
    float* __restrict__ outY, float* __restrict__ outT)
{
    int lane = threadIdx.x & 63;
    int wave = threadIdx.x >> 6;      // 0..3
    int n16 = lane & 15, quad = lane >> 4;
    int b = blockIdx.z;
    int y0 = blockIdx.y * 8;
    int s = blockIdx.x * 4 + wave;    // x-strip 0..39 (37 real)
    int pxbase = 14 * s - 1;
    const bf16* in = inb + (size_t)b * NN * NN * 32;

    short8 wf3[18];
#pragma unroll
    for (int tap = 0; tap < 9; tap++)
#pragma unroll
        for (int t = 0; t < 2; t++)
            wf3[tap * 2 + t] = *(const short8*)(Wr3 + ((tap * 2 + t) * 16 + n16) * 32 + quad * 8);
    short8 wf4[9];
#pragma unroll
    for (int tap = 0; tap < 9; tap++)
        wf4[tap] = *(const short8*)(Wr4 + (tap * 16 + n16) * 32 + quad * 8);
    float4v bias3[2];
#pragma unroll
    for (int t = 0; t < 2; t++)
        bias3[t] = *(const float4v*)(B3 + t * 16 + quad * 4);

    int hpx = pxbase + n16;           // h3 column this lane produces
    bool hvx = (hpx >= 0) && (hpx < NN);
    int gx0 = hpx - 1;                // input col for dx=0
    bool cvx[3];
#pragma unroll
    for (int dx = 0; dx < 3; dx++) {
        int gx = gx0 + dx;
        cvx[dx] = (gx >= 0) && (gx < NN);
    }

    short8 win[3][3];
    auto ldrow = [&](int gy, short8* dst) {
        if (gy >= 0 && gy < NN) {
            const bf16* rowp = in + (size_t)gy * NN * 32 + quad * 8;
#pragma unroll
            for (int dx = 0; dx < 3; dx++) {
                short8 v = {};
                if (cvx[dx]) v = *(const short8*)(rowp + (size_t)(gx0 + dx) * 32);
                dst[dx] = v;
            }
        } else {
            dst[0] = short8{}; dst[1] = short8{}; dst[2] = short8{};
        }
    };
    ldrow(y0 - 2, win[0]);
    ldrow(y0 - 1, win[1]);

    // bpermute indices (bytes). src lane = n16 + 32*(quad&1) (+16 for hi pair)
    int idx_lo = (n16 + 32 * (quad & 1)) * 4;
    int idx_hi = idx_lo + 64;
    int idx_m1 = (lane - 1) * 4;      // pull from lane-1 (garbage at n16=0, discarded)
    int idx_p1 = (lane + 1) * 4;      // pull from lane+1 (garbage at n16=15, discarded)
    bool hi2 = quad >= 2;

    short8 Bring[3];
    bool svalid = s < 37;

#pragma unroll
    for (int k = 0; k < 10; k++) {
        int hy = y0 - 1 + k;
        ldrow(hy + 1, win[(k + 2) % 3]);
        // ---- conv3 for h3 row hy ----
        float4v a3[2] = {bias3[0], bias3[1]};
#pragma unroll
        for (int dy = 0; dy < 3; dy++) {
            short8* row = win[(k + dy) % 3];
#pragma unroll
            for (int dx = 0; dx < 3; dx++) {
                int tap = dy * 3 + dx;
#pragma unroll
                for (int t = 0; t < 2; t++)
                    a3[t] = __builtin_amdgcn_mfma_f32_16x16x32_bf16(wf3[tap * 2 + t], row[dx], a3[t], 0, 0, 0);
            }
        }
        // ---- ReLU + pack + zero-out-of-image (h3 pads with 0 for conv4) ----
        bool live = hvx && (hy >= 0) && (hy < NN);
        unsigned p00 = 0, p01 = 0, p10 = 0, p11 = 0;
        if (live) {
            p00 = pk2(fmaxf(a3[0][0], 0.f), fmaxf(a3[0][1], 0.f));
            p01 = pk2(fmaxf(a3[0][2], 0.f), fmaxf(a3[0][3], 0.f));
            p10 = pk2(fmaxf(a3[1][0], 0.f), fmaxf(a3[1][1], 0.f));
            p11 = pk2(fmaxf(a3[1][2], 0.f), fmaxf(a3[1][3], 0.f));
        }
        // ---- cross-quad repack: C-frag -> K32 B-frag ----
        int q0a = __builtin_amdgcn_ds_bpermute(idx_lo, (int)p00);
        int q1a = __builtin_amdgcn_ds_bpermute(idx_lo, (int)p01);
        int q2a = __builtin_amdgcn_ds_bpermute(idx_hi, (int)p00);
        int q3a = __builtin_amdgcn_ds_bpermute(idx_hi, (int)p01);
        int q0b = __builtin_amdgcn_ds_bpermute(idx_lo, (int)p10);
        int q1b = __builtin_amdgcn_ds_bpermute(idx_lo, (int)p11);
        int q2b = __builtin_amdgcn_ds_bpermute(idx_hi, (int)p10);
        int q3b = __builtin_amdgcn_ds_bpermute(idx_hi, (int)p11);
        int4v bw;
        bw[0] = hi2 ? q0b : q0a;
        bw[1] = hi2 ? q1b : q1a;
        bw[2] = hi2 ? q2b : q2a;
        bw[3] = hi2 ? q3b : q3a;
        Bring[k % 3] = *reinterpret_cast<short8*>(&bw);

        // ---- conv4 for output row y0 + k - 2 ----
        if (k >= 2) {
            int y = y0 + k - 2;
            float4v acc4[3];
#pragma unroll
            for (int dx = 0; dx < 3; dx++) acc4[dx] = (float4v){0.f, 0.f, 0.f, 0.f};
#pragma unroll
            for (int dy = 0; dy < 3; dy++) {
                short8 row = Bring[(k - 2 + dy) % 3];
#pragma unroll
                for (int dx = 0; dx < 3; dx++)
                    acc4[dx] = __builtin_amdgcn_mfma_f32_16x16x32_bf16(wf4[dy * 3 + dx], row, acc4[dx], 0, 0, 0);
            }
            // combine: out[o] = acc4[0][o-1] + acc4[1][o] + acc4[2][o+1]
            float sl = __int_as_float(__builtin_amdgcn_ds_bpermute(idx_m1, __float_as_int(acc4[0][0])));
            float sr = __int_as_float(__builtin_amdgcn_ds_bpermute(idx_p1, __float_as_int(acc4[2][0])));
            float sum = sl + acc4[1][0] + sr;
            if (quad == 0 && n16 >= 1 && n16 <= 14 && svalid) {
                int ox = pxbase + n16;
                if (ox < NN) {
                    int pidx = b * PIMG + y * PW + ox;
                    float vv = addsrc[pidx] + sum;
                    outY[pidx] = vv;
                    outT[b * PIMG + ox * PW + y] = vv;
                }
            }
        }
    }
}

extern "C" void kernel_launch(void* const* d_in, const int* in_sizes, int n_in,
                              void* d_out, int out_size, void* d_ws, size_t ws_size,
                              hipStream_t stream)
{
    const float* x0    = (const float*)d_in[1];
    const float* sg    = (const float*)d_in[2];
    const float* theta = (const float*)d_in[3];
    const float* w1    = (const float*)d_in[5];
    const float* b1    = (const float*)d_in[6];
    const float* w2    = (const float*)d_in[7];
    const float* b2    = (const float*)d_in[8];
    const float* w3    = (const float*)d_in[9];
    const float* b3    = (const float*)d_in[10];
    const float* w4    = (const float*)d_in[11];
    const float* steps = (const float*)d_in[12];

    float* ws = (float*)d_ws;
    float* XP  = ws + O_XP + POFF;    // origin-adjusted padded pointers
    float* YP  = ws + O_YP + POFF;
    float* YPT = ws + O_YPT + POFF;
    float* SP = ws + O_SP;
    float* Q  = ws + O_Q;
    bf16* wr  = (bf16*)(ws + O_WR);
    bf16* h2  = (bf16*)(ws + O_H + H_FLOATS);

    k_prep<<<(2 * PIMG + 255) / 256, 256, 0, stream>>>(theta, w2, w3, w4, x0, ws, wr);

    for (int n = 0; n < NL; n++) {
        // denoiser: fused conv1+2 (XP -> h2), fused in-register conv3+4
        k_conv12<<<dim3(32, 16, NB), 256, 0, stream>>>(
            XP, w1 + n * 288, b1 + n * 32, wr + WR2_OFF + n * 9216, b2 + n * 32, h2);
        k_conv34<<<dim3(10, 64, NB), 256, 0, stream>>>(
            h2, wr + WR3_OFF + n * 9216, b3 + n * 32, wr + WR4_OFF + n * 4608,
            XP, YP, YPT);

        // fused physics path (linearity): XP = YP + steps[n]*bp(sino - F(R(YP)))
        k_radon<<<dim3((ND + 7) / 8, NA, NB), 256, 0, stream>>>(YP, YPT, ws, SP);
        k_filter<<<dim3(3, NB * NA), 256, 0, stream>>>(SP, sg, Q);
        k_backproj_update<<<dim3(32, 32, NB), 256, 0, stream>>>(
            Q, YP, ws, steps, n, XP, (n == NL - 1) ? (float*)d_out : nullptr);
    }
}

// Round 6
// 394.218 us; speedup vs baseline: 1.1054x; 1.0726x over previous
//
#include <hip/hip_runtime.h>
#include <hip/hip_bf16.h>

typedef __hip_bfloat16 bf16;
typedef __attribute__((ext_vector_type(8))) short short8;
typedef __attribute__((ext_vector_type(4))) short s4v;
typedef __attribute__((ext_vector_type(4))) float float4v;

#define NN 512      // image N
#define NA 30       // angles
#define ND 729      // detectors
#define NB 2        // batch
#define NL 3        // iterations
#define BNN (NB*NN*NN)     // 524288
#define BAD (NB*NA*ND)     // 43740

// padded image layout: PH x PW, logical (0,0) at physical (2,2)
#define PW 520
#define PH 516
#define PIMG (PH*PW)       // 268320
#define POFF (2*PW + 2)    // 1042

// ---- workspace float offsets ----
#define O_CS  0
#define O_SN  32
#define O_ICS 64                      // 1/cs per angle
#define O_ISN 96                      // -1/sn per angle
#define O_XP  128                     // 2*PIMG  (current X, padded)
#define O_YP  (O_XP + 2*PIMG)         // 2*PIMG  (Y = X + noise, padded)
#define O_YPT (O_YP + 2*PIMG)         // 2*PIMG  (transposed Y, padded)
#define O_SP  (O_YPT + 2*PIMG)        // BAD
#define O_Q   (O_SP + BAD)            // BAD
#define O_WR  (O_Q + BAD)             // bf16 region: 69120 bf16 = 34560 floats
#define O_H   (((O_WR + 34560) + 15) & ~15)
#define H_FLOATS (NB * 32 * NN * NN / 2)

// repacked weight bf16 offsets within WR region
#define WR2_OFF 0                   // [n][tap][co32][ci32] : 3*9216
#define WR3_OFF 27648               // 3*9216
#define WR4_OFF 55296               // [n][tap][co16][ci32] : 3*4608 (co>0 zero)

// unaligned 8B load (pair of adjacent floats) -> global_load_dwordx2
__device__ __forceinline__ float2 ld2u(const float* p)
{
    float2 r;
    __builtin_memcpy(&r, p, 8);
    return r;
}

// ---- setup: angles + reciprocals + weight repack + image padding, one kernel ----
__global__ void k_prep(const float* __restrict__ theta,
                       const float* __restrict__ w2, const float* __restrict__ w3,
                       const float* __restrict__ w4, const float* __restrict__ x0,
                       float* __restrict__ ws, bf16* __restrict__ wr)
{
    int idx = blockIdx.x * 256 + threadIdx.x;
    if (idx < NA) {
        float t = theta[idx];
        float cs = cosf(t), sn = sinf(t);
        ws[O_CS + idx] = cs;
        ws[O_SN + idx] = sn;
        ws[O_ICS + idx] = 1.0f / cs;      // +-inf ok
        ws[O_ISN + idx] = -1.0f / sn;     // +-inf ok
    }
    if (idx < 2 * 27648) {
        const float* w = (idx < 27648) ? w2 : w3;
        int base = (idx < 27648) ? WR2_OFF : WR3_OFF;
        int r = idx % 27648;
        int n = r / 9216; int r2 = r % 9216;
        int tap = r2 / 1024; int r3 = r2 % 1024;
        int co = r3 / 32, ci = r3 % 32;
        wr[base + r] = __float2bfloat16(w[n * 9216 + (co * 32 + ci) * 9 + tap]);
    } else if (idx < 2 * 27648 + 3 * 4608) {
        int r = idx - 2 * 27648;
        int n = r / 4608; int r2 = r % 4608;
        int tap = r2 / 512; int r3 = r2 % 512;
        int co = r3 / 32, ci = r3 % 32;
        float v = (co == 0) ? w4[n * 288 + ci * 9 + tap] : 0.f;
        wr[WR4_OFF + r] = __float2bfloat16(v);
    }
    if (idx < 2 * PIMG) {
        int b = idx / PIMG, p = idx % PIMG;
        int y = p / PW, x = p % PW;
        bool interior = (y >= 2 && y < 2 + NN && x >= 2 && x < 2 + NN);
        float v = interior ? x0[b * NN * NN + (y - 2) * NN + (x - 2)] : 0.f;
        ws[O_XP + idx] = v;
        if (!interior) {
            ws[O_YP + idx] = 0.f;
            ws[O_YPT + idx] = 0.f;
        }
    }
}

// intersect t-interval with constraint lo < A + tc*coef < hi, via inv = 1/coef
__device__ __forceinline__ void isect2(float A, float inv, float lo, float hi,
                                       float& tlo, float& thi)
{
    float a = (lo - A) * inv, b = (hi - A) * inv;
    tlo = fmaxf(tlo, fminf(a, b));   // NaN (0*inf) dropped by fmin/fmax -> safe
    thi = fminf(thi, fmaxf(a, b));
}

// ---- radon forward: TWO adjacent rays per wave, 32 t-lanes each ----
__global__ __launch_bounds__(256) void k_radon(const float* __restrict__ img,
    const float* __restrict__ imgT, const float* __restrict__ ws,
    float* __restrict__ out)
{
    int b = blockIdx.z, a = blockIdx.y;
    int wave = threadIdx.x >> 6;
    int lane = threadIdx.x & 63;
    int half = lane >> 5, tl = lane & 31;
    int s = blockIdx.x * 8 + wave * 2 + half;
    float cs = ws[O_CS + a], sn = ws[O_SN + a];
    float ics = ws[O_ICS + a], isn = ws[O_ISN + a];
    float s_c = (float)s - 364.0f;
    float A_r = 255.5f + s_c * sn;    // r(t) = A_r + tc*cs
    float A_c = 255.5f + s_c * cs;    // c(t) = A_c - tc*sn

    float tlo = -1e9f, thi = 1e9f;
    isect2(A_r, ics, -1.0f, 512.0f, tlo, thi);
    isect2(A_c, isn, -1.0f, 512.0f, tlo, thi);
    float t0f = fmaxf(tlo + 364.0f, 0.0f);
    float t1f = fminf(thi + 364.0f, 728.0f);

    bool useT = fabsf(cs) >= fabsf(sn);   // wave-uniform
    const float* im = (useT ? imgT : img) + b * PIMG;

    float acc = 0.f;
    if (s < ND && t0f <= t1f) {
        int tb = (int)ceilf(t0f);
        int te = (int)floorf(t1f);
#pragma unroll 2
        for (int t = tb + tl; t <= te; t += 32) {
            float tc = (float)t - 364.0f;
            float r = fmaf(tc, cs, A_r);
            float c = fmaf(-tc, sn, A_c);
            float rf = floorf(r), cf = floorf(c);
            float dr = r - rf, dc = c - cf;
            int irr = (int)rf, icc = (int)cf;
            int idx = useT ? (icc * PW + irr) : (irr * PW + icc);
            float da = useT ? dr : dc;
            float db = useT ? dc : dr;
            float2 p1 = ld2u(im + idx);
            float2 p2 = ld2u(im + idx + PW);
            float u = fmaf(da, p1.y - p1.x, p1.x);
            float w = fmaf(da, p2.y - p2.x, p2.x);
            acc = fmaf(db, w - u, acc + u);
        }
    }
    // butterfly within each 32-lane half (masks <= 16 never cross the half)
    acc += __shfl_xor(acc, 16, 64);
    acc += __shfl_xor(acc, 8, 64);
    acc += __shfl_xor(acc, 4, 64);
    acc += __shfl_xor(acc, 2, 64);
    acc += __shfl_xor(acc, 1, 64);
    if (tl == 0 && s < ND) out[(b * NA + a) * ND + s] = acc;
}

// ---- ramp filter as direct odd-tap convolution: q = sino - scale*conv(sp) ----
__global__ void k_filter(const float* __restrict__ sp, const float* __restrict__ sino,
                         float* __restrict__ q)
{
    __shared__ float row[ND];
    __shared__ float taps[364];
    int ba = blockIdx.y;
    const float* src = sp + ba * ND;
    for (int i = threadIdx.x; i < ND; i += 256) row[i] = src[i];
    const float PI2 = 9.86960440108936f;
    for (int i = threadIdx.x; i < 364; i += 256) {
        float m = (float)(2 * i + 1);
        taps[i] = -2.0f / (PI2 * m * m);
    }
    __syncthreads();
    const float scale = 0.0523598775598299f;  // pi/(2A)
    int d = blockIdx.x * 256 + threadIdx.x;
    if (d < ND) {
        float g0 = 0.5f * row[d], g1 = 0.f;
#pragma unroll 4
        for (int j = 0; j < 364; j += 2) {
            int m0 = 2 * j + 1, m1 = 2 * j + 3;
            float l0 = (d - m0 >= 0) ? row[d - m0] : 0.f;
            float r0 = (d + m0 < ND) ? row[d + m0] : 0.f;
            g0 = fmaf(taps[j], l0 + r0, g0);
            float l1 = (d - m1 >= 0) ? row[d - m1] : 0.f;
            float r1 = (d + m1 < ND) ? row[d + m1] : 0.f;
            g1 = fmaf(taps[j + 1], l1 + r1, g1);
        }
        q[ba * ND + d] = sino[ba * ND + d] - scale * (g0 + g1);
    }
}

// ---- LDS-tiled backprojection + update:  out = src1 + steps[n]*bp(q) ----
__global__ __launch_bounds__(256) void k_backproj_update(const float* __restrict__ q,
    const float* __restrict__ src1, const float* __restrict__ ws,
    const float* __restrict__ steps, int n, float* __restrict__ out,
    float* __restrict__ outcopy)
{
    __shared__ float qt[NA][28];
    __shared__ int dmin_s[NA];
    int b = blockIdx.z;
    int x0 = blockIdx.x * 16, y0 = blockIdx.y * 16;
    int tid = threadIdx.x;
    int lx = tid & 15, ly = tid >> 4;
    const float* qb = q + b * NA * ND;

    for (int idx = tid; idx < NA * 26; idx += 256) {
        int a = idx / 26, j = idx % 26;
        float cs = ws[O_CS + a], sn = ws[O_SN + a];
        float f00 = fmaf(cs, (float)x0 - 255.5f, fmaf(sn, (float)y0 - 255.5f, 364.0f));
        float fmn = f00 + fminf(cs * 15.f, 0.f) + fminf(sn * 15.f, 0.f);
        int dm = (int)floorf(fmn);
        if (j == 0) dmin_s[a] = dm;
        int d = dm + j;
        qt[a][j] = (d >= 0 && d < ND) ? qb[a * ND + d] : 0.f;
    }
    __syncthreads();

    float xc = (float)(x0 + lx) - 255.5f, yc = (float)(y0 + ly) - 255.5f;
    float acc = 0.f;
#pragma unroll
    for (int a = 0; a < NA; a++) {
        float cs = ws[O_CS + a], sn = ws[O_SN + a];
        float f = fmaf(cs, xc, fmaf(sn, yc, 364.0f));
        float lf = floorf(f);
        float w = f - lf;
        int j = (int)lf - dmin_s[a];
        float v0 = qt[a][j], v1 = qt[a][j + 1];
        acc = fmaf(v0, 1.0f - w, fmaf(v1, w, acc));
    }
    int pidx = b * PIMG + (y0 + ly) * PW + (x0 + lx);
    float v = fmaf(steps[n], acc, src1[pidx]);
    out[pidx] = v;
    if (outcopy) {
        int fidx = b * NN * NN + (y0 + ly) * NN + (x0 + lx);
        outcopy[fidx] = v;
        outcopy[fidx + BNN] = v;
        outcopy[fidx + 2 * BNN] = v;
    }
}

// ---- FUSED conv1+conv2: XP -> (h1 halo tile in LDS) -> h2 (HWC bf16 global) ----
__global__ __launch_bounds__(256) void k_conv12(const float* __restrict__ XPb,
    const float* __restrict__ W1, const float* __restrict__ B1,
    const bf16* __restrict__ Wr2, const float* __restrict__ B2,
    bf16* __restrict__ outb)
{
    __shared__ bf16 h1t[34][18][32];
    int b = blockIdx.z;
    int x0 = blockIdx.x * 16;
    int Y0 = blockIdx.y * 32;
    const float* in = XPb + b * PIMG;      // origin-adjusted padded

    // ---- phase A: h1 on halo [Y0-1, Y0+33) x [x0-1, x0+17) ----
    for (int p = threadIdx.x; p < 34 * 18; p += 256) {
        int yy = p / 18, xx = p % 18;
        int gy = Y0 + yy - 1, gx = x0 + xx - 1;
        if (gy < 0 || gy >= NN || gx < 0 || gx >= NN) {
#pragma unroll
            for (int g = 0; g < 4; g++)
                *(short8*)(&h1t[yy][xx][g * 8]) = short8{};
        } else {
            float v[9];
#pragma unroll
            for (int dy = 0; dy < 3; dy++)
#pragma unroll
                for (int dx = 0; dx < 3; dx++)
                    v[dy * 3 + dx] = in[(gy + dy - 1) * PW + (gx + dx - 1)];
#pragma unroll
            for (int g = 0; g < 4; g++) {
                short8 pk;
#pragma unroll
                for (int j = 0; j < 8; j++) {
                    int co = g * 8 + j;
                    float a = B1[co];
                    const float* w = W1 + co * 9;   // block-uniform -> s_load
#pragma unroll
                    for (int k = 0; k < 9; k++) a = fmaf(v[k], w[k], a);
                    a = fmaxf(a, 0.f);
                    bf16 h = __float2bfloat16(a);
                    pk[j] = *reinterpret_cast<short*>(&h);
                }
                *(short8*)(&h1t[yy][xx][g * 8]) = pk;
            }
        }
    }
    __syncthreads();

    // ---- phase B: conv2 (MFMA), h1 from LDS ----
    int lane = threadIdx.x & 63;
    int wave = threadIdx.x >> 6;
    int n16 = lane & 15, quad = lane >> 4;
    int y0w = Y0 + wave * 8;

    short8 wf[18];
#pragma unroll
    for (int tap = 0; tap < 9; tap++)
#pragma unroll
        for (int t = 0; t < 2; t++)
            wf[tap * 2 + t] = *(const short8*)(Wr2 + ((tap * 2 + t) * 16 + n16) * 32 + quad * 8);

    short8 win[3][3];
    auto loadrow = [&](int yy, short8* dst) {
        int ly = yy - (Y0 - 1);   // always in [0,34)
#pragma unroll
        for (int dx = 0; dx < 3; dx++)
            dst[dx] = *(const short8*)(&h1t[ly][n16 + dx][quad * 8]);
    };
    loadrow(y0w - 1, win[0]);
    loadrow(y0w,     win[1]);

    float4v bias[2];
#pragma unroll
    for (int t = 0; t < 2; t++)
        bias[t] = *(const float4v*)(B2 + t * 16 + quad * 4);

    bf16* out = outb + (size_t)b * NN * NN * 32;
#pragma unroll
    for (int i = 0; i < 8; i++) {
        int y = y0w + i;
        loadrow(y + 1, win[(i + 2) % 3]);
        float4v acc[2];
#pragma unroll
        for (int t = 0; t < 2; t++) acc[t] = bias[t];
#pragma unroll
        for (int dy = 0; dy < 3; dy++) {
            short8* row = win[(i + dy) % 3];
#pragma unroll
            for (int dx = 0; dx < 3; dx++) {
                int tap = dy * 3 + dx;
#pragma unroll
                for (int t = 0; t < 2; t++)
                    acc[t] = __builtin_amdgcn_mfma_f32_16x16x32_bf16(wf[tap * 2 + t], row[dx], acc[t], 0, 0, 0);
            }
        }
        bf16* pp = out + ((size_t)y * NN + x0 + n16) * 32 + quad * 4;
#pragma unroll
        for (int t = 0; t < 2; t++) {
            s4v pk;
#pragma unroll
            for (int r = 0; r < 4; r++) {
                float v = fmaxf(acc[t][r], 0.f);
                bf16 h = __float2bfloat16(v);
                pk[r] = *reinterpret_cast<short*>(&h);
            }
            *(s4v*)(pp + t * 16) = pk;
        }
    }
}

// ---- FUSED conv3+conv4, two-phase, 256 threads (4 waves), exact 64-col halo ----
// Tile: 62 output cols; h3 halo = 64 cols = 4 waves x 16 lanes, ZERO dead
// lanes in phase 1 and ZERO idle waves in phase 2 (r2's wave-4 waste removed).
// Phase 1: wave w = col-group w, rolling 3-slot window over 10 h3 rows.
// ONE barrier. Phase 2: all 4 waves, 8 rows each from LDS, overlap-discard
// cols >= 62. YPT direct scatter (r2-exact).
#define C34_W 62
#define C34_H 8
#define C34_PX 64
#define H3S 40     // shorts per px (32 ch + 8 pad) -> 80 B stride

__global__ __launch_bounds__(256) void k_conv34(const bf16* __restrict__ inb,
    const bf16* __restrict__ Wr3, const float* __restrict__ B3,
    const bf16* __restrict__ Wr4, const float* __restrict__ addsrc,
    float* __restrict__ outY, float* __restrict__ outT)
{
    __shared__ bf16 h3s[10][C34_PX][H3S];
    int lane = threadIdx.x & 63;
    int wave = threadIdx.x >> 6;      // 0..3
    int n16 = lane & 15, quad = lane >> 4;
    int b = blockIdx.z;
    int x0 = blockIdx.x * C34_W;
    int y0 = blockIdx.y * C34_H;
    const bf16* in = inb + (size_t)b * NN * NN * 32;

    // ---- phase 1: conv3 for h3 rows y0-1..y0+8, cols x0-1..x0+62 ----
    {
        short8 wf3[18];
#pragma unroll
        for (int tap = 0; tap < 9; tap++)
#pragma unroll
            for (int t = 0; t < 2; t++)
                wf3[tap * 2 + t] = *(const short8*)(Wr3 + ((tap * 2 + t) * 16 + n16) * 32 + quad * 8);
        float4v bias3[2];
#pragma unroll
        for (int t = 0; t < 2; t++)
            bias3[t] = *(const float4v*)(B3 + t * 16 + quad * 4);

        int pxi = wave * 16 + n16;        // h3 col index, 0..63 (all valid)
        int gx0 = x0 + pxi - 2;           // input col for dx=0
        bool cvx[3];
#pragma unroll
        for (int dx = 0; dx < 3; dx++) {
            int gx = gx0 + dx;
            cvx[dx] = (gx >= 0) && (gx < NN);
        }
        int gcol = x0 + pxi - 1;          // image col of this h3 col
        bool colv = (gcol >= 0) && (gcol < NN);

        short8 win[3][3];
        auto ldrow = [&](int gy, short8* dst) {
            if (gy >= 0 && gy < NN) {
                const bf16* rowp = in + (size_t)gy * NN * 32 + quad * 8;
#pragma unroll
                for (int dx = 0; dx < 3; dx++) {
                    short8 v = {};
                    if (cvx[dx]) v = *(const short8*)(rowp + (size_t)(gx0 + dx) * 32);
                    dst[dx] = v;
                }
            } else {
                dst[0] = short8{}; dst[1] = short8{}; dst[2] = short8{};
            }
        };
        ldrow(y0 - 2, win[0]);
        ldrow(y0 - 1, win[1]);
#pragma unroll
        for (int r = 0; r < 10; r++) {
            int hy = y0 - 1 + r;
            ldrow(hy + 1, win[(r + 2) % 3]);
            float4v a3[2] = {bias3[0], bias3[1]};
#pragma unroll
            for (int dy = 0; dy < 3; dy++) {
                short8* row = win[(r + dy) % 3];
#pragma unroll
                for (int dx = 0; dx < 3; dx++) {
                    int tap = dy * 3 + dx;
#pragma unroll
                    for (int t = 0; t < 2; t++)
                        a3[t] = __builtin_amdgcn_mfma_f32_16x16x32_bf16(wf3[tap * 2 + t], row[dx], a3[t], 0, 0, 0);
                }
            }
            bool rowv = (hy >= 0) && (hy < NN);
            bool live = rowv && colv;
#pragma unroll
            for (int t = 0; t < 2; t++) {
                s4v pk = {};
                if (live) {
#pragma unroll
                    for (int r2 = 0; r2 < 4; r2++) {
                        float v = fmaxf(a3[t][r2], 0.f);
                        bf16 h = __float2bfloat16(v);
                        pk[r2] = *reinterpret_cast<short*>(&h);
                    }
                }
                *(s4v*)(&h3s[r][pxi][t * 16 + quad * 4]) = pk;
            }
        }
    }
    __syncthreads();

    // ---- phase 2: conv4 from LDS, all 4 waves, 8 rows each ----
    {
        short8 wf4[9];
#pragma unroll
        for (int tap = 0; tap < 9; tap++)
            wf4[tap] = *(const short8*)(Wr4 + (tap * 16 + n16) * 32 + quad * 8);

        int c = wave * 16 + n16;          // local out col 0..63; valid < C34_W
        int cr = (c > C34_W - 1) ? (C34_W - 1) : c;   // clamp reads (c=62,63 masked)
        bool cok = (c < C34_W) && (x0 + c < NN);
        short8 hw[3][3];
        auto ldh = [&](int r, short8* dst) {
#pragma unroll
            for (int dx = 0; dx < 3; dx++)
                dst[dx] = *(const short8*)(&h3s[r][cr + dx][quad * 8]);
        };
        ldh(0, hw[0]);
        ldh(1, hw[1]);
#pragma unroll
        for (int i = 0; i < 8; i++) {
            ldh(i + 2, hw[(i + 2) % 3]);
            float4v a4 = {0.f, 0.f, 0.f, 0.f};
#pragma unroll
            for (int dy = 0; dy < 3; dy++) {
                short8* row = hw[(i + dy) % 3];
#pragma unroll
                for (int dx = 0; dx < 3; dx++)
                    a4 = __builtin_amdgcn_mfma_f32_16x16x32_bf16(wf4[dy * 3 + dx], row[dx], a4, 0, 0, 0);
            }
            if (quad == 0 && cok) {
                int px = x0 + c;
                int y = y0 + i;
                int pidx = b * PIMG + y * PW + px;
                float vv = addsrc[pidx] + a4[0];
                outY[pidx] = vv;
                outT[b * PIMG + px * PW + y] = vv;
            }
        }
    }
}

extern "C" void kernel_launch(void* const* d_in, const int* in_sizes, int n_in,
                              void* d_out, int out_size, void* d_ws, size_t ws_size,
                              hipStream_t stream)
{
    const float* x0    = (const float*)d_in[1];
    const float* sg    = (const float*)d_in[2];
    const float* theta = (const float*)d_in[3];
    const float* w1    = (const float*)d_in[5];
    const float* b1    = (const float*)d_in[6];
    const float* w2    = (const float*)d_in[7];
    const float* b2    = (const float*)d_in[8];
    const float* w3    = (const float*)d_in[9];
    const float* b3    = (const float*)d_in[10];
    const float* w4    = (const float*)d_in[11];
    const float* steps = (const float*)d_in[12];

    float* ws = (float*)d_ws;
    float* XP  = ws + O_XP + POFF;    // origin-adjusted padded pointers
    float* YP  = ws + O_YP + POFF;
    float* YPT = ws + O_YPT + POFF;
    float* SP = ws + O_SP;
    float* Q  = ws + O_Q;
    bf16* wr  = (bf16*)(ws + O_WR);
    bf16* h2  = (bf16*)(ws + O_H + H_FLOATS);

    k_prep<<<(2 * PIMG + 255) / 256, 256, 0, stream>>>(theta, w2, w3, w4, x0, ws, wr);

    for (int n = 0; n < NL; n++) {
        // denoiser: fused conv1+2 (XP -> h2), fused conv3+4 (h2 -> YP/YPT)
        k_conv12<<<dim3(32, 16, NB), 256, 0, stream>>>(
            XP, w1 + n * 288, b1 + n * 32, wr + WR2_OFF + n * 9216, b2 + n * 32, h2);
        k_conv34<<<dim3(9, 64, NB), 256, 0, stream>>>(
            h2, wr + WR3_OFF + n * 9216, b3 + n * 32, wr + WR4_OFF + n * 4608,
            XP, YP, YPT);

        // fused physics path (linearity): XP = YP + steps[n]*bp(sino - F(R(YP)))
        k_radon<<<dim3((ND + 7) / 8, NA, NB), 256, 0, stream>>>(YP, YPT, ws, SP);
        k_filter<<<dim3(3, NB * NA), 256, 0, stream>>>(SP, sg, Q);
        k_backproj_update<<<dim3(32, 32, NB), 256, 0, stream>>>(
            Q, YP, ws, steps, n, XP, (n == NL - 1) ? (float*)d_out : nullptr);
    }
}